// Round 1
// baseline (240.095 us; speedup 1.0000x reference)
//
#include <hip/hip_runtime.h>

#define D 64

// ---------------- rel kernel: R = rel_emb @ Wf^T ; rel_out = rel_emb @ Wrel^T
__global__ __launch_bounds__(64) void rel_kernel(
    const float* __restrict__ rel_emb,
    const float* __restrict__ W_f,
    const float* __restrict__ W_rel,
    float* __restrict__ R,
    float* __restrict__ rel_out,
    int n_rel) {
  int r = blockIdx.x;
  if (r >= n_rel) return;
  int j = threadIdx.x;  // 0..63 = output column
  float v = rel_emb[r * D + j];
  float accR = 0.f, accO = 0.f;
#pragma unroll 16
  for (int k = 0; k < D; ++k) {
    float a = __shfl(v, k);
    accR += a * W_f[j * D + k];
    accO += a * W_rel[j * D + k];
  }
  R[r * D + j] = accR;
  rel_out[r * D + j] = accO;
}

// ---------------- node kernel: out = nf @ Wself^T + bias ; X = nf @ Wf^T
__global__ __launch_bounds__(256) void node_kernel(
    const float* __restrict__ nf,
    const float* __restrict__ W_self,
    const float* __restrict__ W_f,
    const float* __restrict__ bias,
    float* __restrict__ out,
    float* __restrict__ X,
    int n_nodes) {
  __shared__ float WtS[D][D];   // WtS[k][j] = W_self[j][k]
  __shared__ float WtF[D][D];
  __shared__ float tile[16 * D];

  int tid = threadIdx.x;
  for (int idx = tid; idx < D * D; idx += 256) {
    int j = idx >> 6, k = idx & 63;
    WtS[k][j] = W_self[idx];
    WtF[k][j] = W_f[idx];
  }
  int lane = tid & 63;
  int wave = tid >> 6;
  float b = bias[lane];
  __syncthreads();

  int tile_base = blockIdx.x * 16;
  if (tile_base >= n_nodes) return;
  int nrows = min(16, n_nodes - tile_base);

  // stage 16 node rows (1024 floats) via float4, coalesced
  if (nrows == 16) {
    ((float4*)tile)[tid] = ((const float4*)nf)[tile_base * 16 + tid];
  } else {
    for (int idx = tid; idx < nrows * D; idx += 256)
      tile[idx] = nf[tile_base * D + idx];
  }
  __syncthreads();

  for (int r = wave; r < nrows; r += 4) {
    const float* row = &tile[r * D];
    float accS = 0.f, accF = 0.f;
#pragma unroll
    for (int k = 0; k < D; k += 4) {
      float4 a = *(const float4*)(row + k);  // broadcast (same addr all lanes)
      accS += a.x * WtS[k + 0][lane];
      accF += a.x * WtF[k + 0][lane];
      accS += a.y * WtS[k + 1][lane];
      accF += a.y * WtF[k + 1][lane];
      accS += a.z * WtS[k + 2][lane];
      accF += a.z * WtF[k + 2][lane];
      accS += a.w * WtS[k + 3][lane];
      accF += a.w * WtF[k + 3][lane];
    }
    int node = tile_base + r;
    out[node * D + lane] = accS + b;
    X[node * D + lane] = accF;
  }
}

// ---------------- edge kernel: out[dst] += X[src] - R[etype]  (forward edges)
__global__ __launch_bounds__(256) void edge_kernel(
    const int* __restrict__ src, const int* __restrict__ dst,
    const int* __restrict__ et, const int* __restrict__ dir,
    const float* __restrict__ X, const float* __restrict__ R,
    float* __restrict__ out, int n_edges) {
  int lane = threadIdx.x & 63;
  int wave_id = (int)((blockIdx.x * blockDim.x + threadIdx.x) >> 6);
  int n_waves = (int)((gridDim.x * blockDim.x) >> 6);

  for (long long base = (long long)wave_id * 64; base < n_edges;
       base += (long long)n_waves * 64) {
    int e = (int)base + lane;
    int s_l = 0, d_l = 0, t_l = 0, dir_l = 1;
    if (e < n_edges) {
      s_l = src[e];  // coalesced: 64 consecutive edges per wave
      d_l = dst[e];
      t_l = et[e];
      dir_l = dir[e];
    }
    int cnt = min(64, n_edges - (int)base);
    for (int i = 0; i < cnt; ++i) {
      int dir_i = __shfl(dir_l, i);     // uniform across wave
      if (dir_i != 0) continue;         // backward edges contribute zero
      int s_i = __shfl(s_l, i);
      int t_i = __shfl(t_l, i);
      int d_i = __shfl(d_l, i);
      float val = X[s_i * D + lane] - R[t_i * D + lane];
      atomicAdd(&out[d_i * D + lane], val);
    }
  }
}

extern "C" void kernel_launch(void* const* d_in, const int* in_sizes, int n_in,
                              void* d_out, int out_size, void* d_ws, size_t ws_size,
                              hipStream_t stream) {
  const float* node_feat = (const float*)d_in[0];
  const float* rel_emb   = (const float*)d_in[1];
  const int*   src       = (const int*)d_in[2];
  const int*   dst       = (const int*)d_in[3];
  const int*   etype     = (const int*)d_in[4];
  const int*   direction = (const int*)d_in[5];
  const float* W_self    = (const float*)d_in[6];
  const float* W_forward = (const float*)d_in[7];
  // d_in[8] = W_backward (unused: backward edges are masked to zero)
  const float* W_rel     = (const float*)d_in[9];
  const float* bias      = (const float*)d_in[10];

  int n_nodes = in_sizes[0] / D;
  int n_rel   = in_sizes[1] / D;
  int n_edges = in_sizes[2];

  float* out     = (float*)d_out;                 // [n_nodes, 64]
  float* rel_out = out + (size_t)n_nodes * D;     // [n_rel, 64]

  float* X = (float*)d_ws;                        // [n_nodes, 64]
  float* R = X + (size_t)n_nodes * D;             // [n_rel, 64]

  // 1) R and rel_out (independent, tiny)
  rel_kernel<<<n_rel, 64, 0, stream>>>(rel_emb, W_forward, W_rel, R, rel_out, n_rel);

  // 2) out = nf@Ws^T + bias ; X = nf@Wf^T
  int n_tiles = (n_nodes + 15) / 16;
  node_kernel<<<n_tiles, 256, 0, stream>>>(node_feat, W_self, W_forward, bias,
                                           out, X, n_nodes);

  // 3) scatter-add forward edge messages
  edge_kernel<<<2048, 256, 0, stream>>>(src, dst, etype, direction, X, R, out,
                                        n_edges);
}